// Round 14
// baseline (409.429 us; speedup 1.0000x reference)
//
#include <hip/hip_runtime.h>
#include <hip/hip_bf16.h>
#include <float.h>
#include <math.h>

#define NB 32
#define NS 4096
#define NE 1024
#define ND 1024
#define NA 512

typedef __attribute__((ext_vector_type(4))) float f32x4;
typedef __attribute__((ext_vector_type(8))) short short8;
typedef __attribute__((ext_vector_type(4))) ushort ushort4v;
typedef __attribute__((address_space(3))) char lds_char_t;
typedef __attribute__((address_space(1))) const char g_char_t;

static __device__ __forceinline__ ushort f2bf(float f){
    union { float f; unsigned int u; } x; x.f = f;
    unsigned int u = x.u + 0x7fffu + ((x.u >> 16) & 1u);
    return (ushort)(u >> 16);
}

static __device__ __forceinline__ float bf2f(ushort h){
    union { unsigned int u; float f; } x; x.u = ((unsigned int)h) << 16;
    return x.f;
}

static __device__ __forceinline__ float tanh_fast(float x){
    float e = __expf(2.f * x);
    return 1.f - 2.f / (e + 1.f);
}

// ---- K1a: W_h (1024x512 f32) -> WTf bf16 in MFMA-fragment order ----
__global__ __launch_bounds__(256) void k_prep_wtf(const float* __restrict__ Wh,
                                                  ushort* __restrict__ WTf){
    int i = blockIdx.x * 256 + threadIdx.x;   // 524288 outputs
    int e = i & 7;
    int lane = (i >> 3) & 63;
    int ng = (i >> 9) & 31;
    int s = i >> 14;
    int k = s * 32 + (lane >> 4) * 8 + e;
    int col = ng * 16 + (lane & 15);
    WTf[i] = f2bf(Wh[k * NA + col]);
}

// ---- K1b: proj_dec partials ----
__global__ __launch_bounds__(512) void k_projdec(const float* __restrict__ dec,
                                                 const float* __restrict__ Ws,
                                                 float* __restrict__ pdp){
    int b = blockIdx.x >> 2, kc = blockIdx.x & 3;
    int a = threadIdx.x;
    const float* dp = dec + b * ND + kc * 256;
    const float* wp = Ws + (size_t)(kc * 256) * NA + a;
    float acc = 0.f;
    #pragma unroll 4
    for (int k = 0; k < 256; k++) acc += dp[k] * wp[(size_t)k * NA];
    pdp[(kc * NB + b) * NA + a] = acc;
}

// ---- K1c: E (f32) -> E16 (bf16), one clean streaming pass ----
__global__ __launch_bounds__(256) void k_cvt_e(const float* __restrict__ E,
                                               ushort* __restrict__ E16){
    const size_t nchunks = (size_t)NB * NS * NE / 8;   // 16,777,216
    const size_t stride = (size_t)gridDim.x * 256;
    for (size_t c = (size_t)blockIdx.x * 256 + threadIdx.x; c < nchunks; c += stride){
        const f32x4* p = (const f32x4*)(E + c * 8);
        f32x4 lo = p[0], hi = p[1];
        short8 h;
        #pragma unroll
        for (int e = 0; e < 4; e++){
            h[e]     = (short)f2bf(lo[e]);
            h[e + 4] = (short)f2bf(hi[e]);
        }
        *(short8*)(E16 + c * 8) = h;
    }
}

// ---- K2 (new): fused scores GEMM over bf16 E via global_load_lds ring. ----
// BM=128, BN=128 (bn quarter), BK=64, 4 waves (2x2), 256 thr, 3 blocks/CU.
// 3-slot LDS ring, counted vmcnt (never 0 in loop), pre-swizzled DMA source,
// bank-uniform ds_read_b128, ZERO conversion work in the K-loop.
__global__ __launch_bounds__(256, 3) void k_scores16(const ushort* __restrict__ E16,
                                                     const ushort* __restrict__ WTf,
                                                     const float* __restrict__ pdp,
                                                     const float* __restrict__ v,
                                                     float* __restrict__ scrp){
    const int t = threadIdx.x;
    const int lane = t & 63, w = t >> 6;
    const int l15 = lane & 15, grp = lane >> 4;
    const int wm = w >> 1, wn = w & 1;

    // XCD-major mapping: 4096 blocks; 4 bn-quarters of one m-tile adjacent.
    const int bid = blockIdx.x;
    const int xcd = bid & 7, slot = bid >> 3;
    const int mblk = xcd * 128 + (slot >> 2);     // 0..1023
    const int bn = slot & 3;
    const int m0 = mblk << 7;                     // 128-row base
    const int b = mblk >> 5;                      // batch

    __shared__ __align__(16) ushort ring[3][128 * 64];  // 3 x 16KB bf16 tiles
    __shared__ float sc[128][2];

    // DMA: instr j covers chunks c = (w*4+j)*64 + lane; c -> (row=c>>3, q=c&7).
    // Source seg pre-swizzled: qs = q ^ (row&7); LDS dest linear (uniform+lane*16).
    auto dma = [&](int it){
        char* bufp = (char*)&ring[it % 3][0];
        #pragma unroll
        for (int j = 0; j < 4; ++j){
            const int c = (w * 4 + j) * 64 + lane;
            const int row = c >> 3, q = c & 7;
            const int qs = q ^ (row & 7);
            const ushort* src = E16 + (size_t)(m0 + row) * NE + it * 64 + qs * 8;
            __builtin_amdgcn_global_load_lds((g_char_t*)src,
                                             (lds_char_t*)(bufp + c * 16), 16, 0, 0);
        }
    };

    f32x4 acc[4][4];
    f32x4 zero; zero[0]=0.f; zero[1]=0.f; zero[2]=0.f; zero[3]=0.f;
    #pragma unroll
    for (int m = 0; m < 4; m++)
        #pragma unroll
        for (int n = 0; n < 4; n++) acc[m][n] = zero;

    // B-frag base: ng = bn*8 + wn*4 + n; k-slice s at +s*16384 ushorts
    const ushort* wtf0 = WTf + ((size_t)(bn * 8 + wn * 4) * 64 + lane) * 8;

    // prologue: dma(0), dma(1); wait dma(0) (counted); barrier
    dma(0);
    dma(1);
    asm volatile("s_waitcnt vmcnt(4)" ::: "memory");
    __builtin_amdgcn_s_barrier();

    for (int it = 0; it < 16; ++it){
        // 1) wt loads for both kk (OLDEST vmem this iter; L2-hot)
        short8 wt0[4], wt1[4];
        const ushort* wp = wtf0 + (size_t)(2 * it) * 16384;
        #pragma unroll
        for (int n = 0; n < 4; n++) wt0[n] = *(const short8*)(wp + n * 512);
        #pragma unroll
        for (int n = 0; n < 4; n++) wt1[n] = *(const short8*)(wp + 16384 + n * 512);
        __builtin_amdgcn_sched_barrier(0);
        // 2) DMA tile it+2 (NEWEST; never drained this iter)
        if (it < 14) dma(it + 2);
        __builtin_amdgcn_sched_barrier(0);
        // 3) compute: wt-wait (counted) retires dma(it+1); dma(it+2) stays in flight
        const char* base = (const char*)&ring[it % 3][0];
        #pragma unroll
        for (int kk = 0; kk < 2; kk++){
            #pragma unroll
            for (int m = 0; m < 4; m++){
                const int r = wm * 64 + m * 16 + l15;
                short8 af = *(const short8*)(base + r * 128 + (((kk * 4 + grp) ^ (r & 7)) << 4));
                short8* wtk = kk ? wt1 : wt0;
                #pragma unroll
                for (int n = 0; n < 4; n++)
                    acc[m][n] = __builtin_amdgcn_mfma_f32_16x16x32_bf16(af, wtk[n], acc[m][n], 0, 0, 0);
            }
        }
        __builtin_amdgcn_sched_barrier(0);
        // 4) tile it+1 ready for all waves (outstanding = dma(it+2) only)
        if (it < 15){
            asm volatile("s_waitcnt vmcnt(4)" ::: "memory");
            __builtin_amdgcn_s_barrier();
        }
    }

    // epilogue: +proj_dec, fast-tanh, v-dot, reduce over this block's 128 cols
    float pdc[4], vc[4];
    #pragma unroll
    for (int n = 0; n < 4; n++){
        int c = bn * 128 + wn * 64 + n * 16 + l15;
        float p = 0.f;
        #pragma unroll
        for (int kc = 0; kc < 4; kc++) p += pdp[(kc * NB + b) * NA + c];
        pdc[n] = p;
        vc[n] = v[c];
    }
    #pragma unroll
    for (int m = 0; m < 4; m++){
        #pragma unroll
        for (int j = 0; j < 4; j++){
            float s = 0.f;
            #pragma unroll
            for (int n = 0; n < 4; n++) s += tanh_fast(acc[m][n][j] + pdc[n]) * vc[n];
            s += __shfl_xor(s, 1);
            s += __shfl_xor(s, 2);
            s += __shfl_xor(s, 4);
            s += __shfl_xor(s, 8);
            if (l15 == 0) sc[wm * 64 + m * 16 + grp * 4 + j][wn] = s;
        }
    }
    __syncthreads();
    if (t < 128)
        scrp[(size_t)bn * (NB * NS) + m0 + t] = sc[t][0] + sc[t][1];
}

// ---- K4 (new): context over bf16 E ----
__global__ __launch_bounds__(1024) void k_context16(const ushort* __restrict__ E16,
                                                    const float* __restrict__ weights,
                                                    float* __restrict__ part){
    int b = blockIdx.x >> 3, ch = blockIdx.x & 7;
    int t = threadIdx.x;
    int h = t >> 8, tg = t & 255;
    __shared__ float wsm[512];
    __shared__ __align__(16) f32x4 red[4][256];
    if (t < 512) wsm[t] = weights[b * NS + ch * 512 + t];
    __syncthreads();
    const ushort* Ep = E16 + ((size_t)b * NS + ch * 512 + h * 128) * NE + tg * 4;
    f32x4 acc; acc[0]=0.f; acc[1]=0.f; acc[2]=0.f; acc[3]=0.f;
    #pragma unroll 4
    for (int s = 0; s < 128; s++){
        ushort4v u = *(const ushort4v*)(Ep + (size_t)s * NE);
        float w = wsm[h * 128 + s];
        acc[0] += w * bf2f(u[0]); acc[1] += w * bf2f(u[1]);
        acc[2] += w * bf2f(u[2]); acc[3] += w * bf2f(u[3]);
    }
    red[h][tg] = acc;
    __syncthreads();
    if (h == 0){
        f32x4 a0 = red[0][tg], a1 = red[1][tg], a2 = red[2][tg], a3 = red[3][tg];
        f32x4 s;
        s[0] = a0[0]+a1[0]+a2[0]+a3[0];
        s[1] = a0[1]+a1[1]+a2[1]+a3[1];
        s[2] = a0[2]+a1[2]+a2[2]+a3[2];
        s[3] = a0[3]+a1[3]+a2[3]+a3[3];
        *(f32x4*)(part + ((size_t)(b * 8 + ch)) * NE + tg * 4) = s;
    }
}

// ================= fallback (R13) kernels =================
__global__ __launch_bounds__(256, 3) void k_scores(const float* __restrict__ E,
                                                   const ushort* __restrict__ WTf,
                                                   const float* __restrict__ pdp,
                                                   const float* __restrict__ v,
                                                   float* __restrict__ scrp){
    const int t = threadIdx.x;
    const int lane = t & 63, w = t >> 6;
    const int l15 = lane & 15, grp = lane >> 4;
    const int wm = w >> 1, wn = w & 1;
    const int bid = blockIdx.x;
    const int xcd = bid & 7, slot = bid >> 3;
    const int mblk = xcd * 128 + (slot >> 2);
    const int bn = slot & 3;
    const int m0 = mblk << 7;
    const int b = mblk >> 5;

    __shared__ __align__(16) ushort bft[2][128 * 32];
    __shared__ float sc[128][2];

    const int sr = t >> 1, half = t & 1;
    const float* gsrc = E + (size_t)(m0 + sr) * NE + half * 16;

    f32x4 acc[4][4];
    f32x4 zero; zero[0]=0.f; zero[1]=0.f; zero[2]=0.f; zero[3]=0.f;
    #pragma unroll
    for (int m = 0; m < 4; m++)
        #pragma unroll
        for (int n = 0; n < 4; n++) acc[m][n] = zero;

    f32x4 st[4];
    auto stage_load = [&](int it){
        const f32x4* p = (const f32x4*)(gsrc + it * 32);
        st[0] = p[0]; st[1] = p[1]; st[2] = p[2]; st[3] = p[3];
    };
    auto stage_write = [&](int buf){
        short8 h0, h1;
        #pragma unroll
        for (int e = 0; e < 4; e++){
            h0[e]     = (short)f2bf(st[0][e]);
            h0[e + 4] = (short)f2bf(st[1][e]);
            h1[e]     = (short)f2bf(st[2][e]);
            h1[e + 4] = (short)f2bf(st[3][e]);
        }
        char* bb = (char*)&bft[buf][0];
        unsigned s0 = (unsigned)(half * 2);
        *(short8*)(bb + sr * 64 + (((s0    ) ^ (unsigned)(sr & 3)) << 4)) = h0;
        *(short8*)(bb + sr * 64 + (((s0 + 1) ^ (unsigned)(sr & 3)) << 4)) = h1;
    };

    const ushort* wtf0 = WTf + ((size_t)(bn * 8 + wn * 4) * 64 + lane) * 8;

    stage_load(0);
    stage_write(0);
    asm volatile("s_waitcnt lgkmcnt(0)" ::: "memory");
    __builtin_amdgcn_s_barrier();

    for (int it = 0; it < 32; ++it){
        const int buf = it & 1;
        short8 wt[4];
        const ushort* wp = wtf0 + (size_t)it * 16384;
        #pragma unroll
        for (int n = 0; n < 4; n++) wt[n] = *(const short8*)(wp + n * 512);
        __builtin_amdgcn_sched_barrier(0);
        if (it < 31) stage_load(it + 1);
        __builtin_amdgcn_sched_barrier(0);
        const char* base = (const char*)&bft[buf][0];
        #pragma unroll
        for (int m = 0; m < 4; m++){
            const int r = wm * 64 + m * 16 + l15;
            short8 af = *(const short8*)(base + r * 64 + (((unsigned)grp ^ (unsigned)(r & 3)) << 4));
            #pragma unroll
            for (int n = 0; n < 4; n++)
                acc[m][n] = __builtin_amdgcn_mfma_f32_16x16x32_bf16(af, wt[n], acc[m][n], 0, 0, 0);
        }
        __builtin_amdgcn_sched_barrier(0);
        if (it < 31) stage_write(buf ^ 1);
        asm volatile("s_waitcnt lgkmcnt(0)" ::: "memory");
        __builtin_amdgcn_s_barrier();
    }

    float pdc[4], vc[4];
    #pragma unroll
    for (int n = 0; n < 4; n++){
        int c = bn * 128 + wn * 64 + n * 16 + l15;
        float p = 0.f;
        #pragma unroll
        for (int kc = 0; kc < 4; kc++) p += pdp[(kc * NB + b) * NA + c];
        pdc[n] = p;
        vc[n] = v[c];
    }
    #pragma unroll
    for (int m = 0; m < 4; m++){
        #pragma unroll
        for (int j = 0; j < 4; j++){
            float s = 0.f;
            #pragma unroll
            for (int n = 0; n < 4; n++) s += tanh_fast(acc[m][n][j] + pdc[n]) * vc[n];
            s += __shfl_xor(s, 1);
            s += __shfl_xor(s, 2);
            s += __shfl_xor(s, 4);
            s += __shfl_xor(s, 8);
            if (l15 == 0) sc[wm * 64 + m * 16 + grp * 4 + j][wn] = s;
        }
    }
    __syncthreads();
    if (t < 128)
        scrp[(size_t)bn * (NB * NS) + m0 + t] = sc[t][0] + sc[t][1];
}

__global__ __launch_bounds__(1024) void k_context(const float* __restrict__ E,
                                                  const float* __restrict__ weights,
                                                  float* __restrict__ part){
    int b = blockIdx.x >> 3, ch = blockIdx.x & 7;
    int t = threadIdx.x;
    int h = t >> 8, tg = t & 255;
    __shared__ float wsm[512];
    __shared__ __align__(16) f32x4 red[4][256];
    if (t < 512) wsm[t] = weights[b * NS + ch * 512 + t];
    __syncthreads();
    const f32x4* Ep = (const f32x4*)(E + ((size_t)b * NS + ch * 512 + h * 128) * NE) + tg;
    f32x4 acc; acc[0]=0.f; acc[1]=0.f; acc[2]=0.f; acc[3]=0.f;
    #pragma unroll 4
    for (int s = 0; s < 128; s++){
        f32x4 e = Ep[(size_t)s * 256];
        float w = wsm[h * 128 + s];
        acc[0] += w * e[0]; acc[1] += w * e[1];
        acc[2] += w * e[2]; acc[3] += w * e[3];
    }
    red[h][tg] = acc;
    __syncthreads();
    if (h == 0){
        f32x4 a0 = red[0][tg], a1 = red[1][tg], a2 = red[2][tg], a3 = red[3][tg];
        f32x4 s;
        s[0] = a0[0]+a1[0]+a2[0]+a3[0];
        s[1] = a0[1]+a1[1]+a2[1]+a3[1];
        s[2] = a0[2]+a1[2]+a2[2]+a3[2];
        s[3] = a0[3]+a1[3]+a2[3]+a3[3];
        *(f32x4*)(part + ((size_t)(b * 8 + ch)) * NE + tg * 4) = s;
    }
}
// ================= end fallback =================

// ---- K3: masked softmax; sums the four N-quarter score partials ----
__global__ __launch_bounds__(256) void k_softmax(const float* __restrict__ scrp,
                                                 const int* __restrict__ mask,
                                                 float* __restrict__ weights){
    int b = blockIdx.x, t = threadIdx.x;
    __shared__ float red[8];
    float vals[16];
    float mx = -FLT_MAX;
    #pragma unroll
    for (int i = 0; i < 16; i++){
        int s = i * 256 + t;
        float x = scrp[b * NS + s]
                + scrp[(size_t)(NB * NS) + b * NS + s]
                + scrp[2 * (size_t)(NB * NS) + b * NS + s]
                + scrp[3 * (size_t)(NB * NS) + b * NS + s];
        x = (mask[b * NS + s] != 0) ? x : -FLT_MAX;
        vals[i] = x;
        mx = fmaxf(mx, x);
    }
    #pragma unroll
    for (int off = 32; off; off >>= 1) mx = fmaxf(mx, __shfl_xor(mx, off));
    int wv = t >> 6;
    if ((t & 63) == 0) red[wv] = mx;
    __syncthreads();
    mx = fmaxf(fmaxf(red[0], red[1]), fmaxf(red[2], red[3]));
    float sum = 0.f;
    #pragma unroll
    for (int i = 0; i < 16; i++){ vals[i] = __expf(vals[i] - mx); sum += vals[i]; }
    #pragma unroll
    for (int off = 32; off; off >>= 1) sum += __shfl_xor(sum, off);
    if ((t & 63) == 0) red[4 + wv] = sum;
    __syncthreads();
    sum = red[4] + red[5] + red[6] + red[7];
    float inv = 1.f / sum;
    #pragma unroll
    for (int i = 0; i < 16; i++) weights[b * NS + i * 256 + t] = vals[i] * inv;
}

// ---- K5: reduce context partials ----
__global__ __launch_bounds__(256) void k_reduce_ctx(const float* __restrict__ part,
                                                    float* __restrict__ ctx){
    int i = blockIdx.x * 256 + threadIdx.x;  // 32768
    int b = i >> 10, e = i & 1023;
    float s = 0.f;
    #pragma unroll
    for (int ch = 0; ch < 8; ch++) s += part[((size_t)(b * 8 + ch)) * NE + e];
    ctx[i] = s;
}

extern "C" void kernel_launch(void* const* d_in, const int* in_sizes, int n_in,
                              void* d_out, int out_size, void* d_ws, size_t ws_size,
                              hipStream_t stream){
    const float* dec  = (const float*)d_in[0];
    const float* E    = (const float*)d_in[1];
    const int*   mask = (const int*)d_in[2];
    const float* Wh   = (const float*)d_in[3];
    const float* Ws   = (const float*)d_in[4];
    const float* v    = (const float*)d_in[5];
    float* ctx = (float*)d_out;               // (32,1024)
    float* weights = (float*)d_out + NB * NE; // (32,4096)

    char* ws = (char*)d_ws;
    const size_t e16_bytes  = (size_t)NB * NS * NE * 2;   // 256 MB
    const size_t need = e16_bytes + (1 << 20) + (256 << 10) + (2 << 20) + (1 << 20);

    if (ws_size >= need){
        // ---- bf16-E pipeline ----
        ushort* E16  = (ushort*)ws;
        ushort* WTf  = (ushort*)(ws + e16_bytes);
        float*  pdp  = (float*)(ws + e16_bytes + (1 << 20));
        float*  scrp = (float*)(ws + e16_bytes + (1 << 20) + (256 << 10));
        float*  part = (float*)(ws + e16_bytes + (1 << 20) + (256 << 10) + (2 << 20));

        k_prep_wtf<<<2048, 256, 0, stream>>>(Wh, WTf);
        k_projdec<<<128, 512, 0, stream>>>(dec, Ws, pdp);
        k_cvt_e<<<4096, 256, 0, stream>>>(E, E16);
        k_scores16<<<4096, 256, 0, stream>>>(E16, WTf, pdp, v, scrp);
        k_softmax<<<32, 256, 0, stream>>>(scrp, mask, weights);
        k_context16<<<256, 1024, 0, stream>>>(E16, weights, part);
        k_reduce_ctx<<<128, 256, 0, stream>>>(part, ctx);
    } else {
        // ---- fallback: R13 f32 pipeline ----
        ushort* WTf  = (ushort*)ws;
        float*  part = (float*)ws;
        float*  pdp  = (float*)(ws + (1 << 20));
        float*  scrp = (float*)(ws + (1 << 20) + (256 << 10));

        k_prep_wtf<<<2048, 256, 0, stream>>>(Wh, WTf);
        k_projdec<<<128, 512, 0, stream>>>(dec, Ws, pdp);
        k_scores<<<4096, 256, 0, stream>>>(E, WTf, pdp, v, scrp);
        k_softmax<<<32, 256, 0, stream>>>(scrp, mask, weights);
        k_context<<<256, 1024, 0, stream>>>(E, weights, part);
        k_reduce_ctx<<<128, 256, 0, stream>>>(part, ctx);
    }
}